// Round 6
// baseline (542.906 us; speedup 1.0000x reference)
//
#include <hip/hip_runtime.h>

typedef __attribute__((ext_vector_type(8))) short bf16x8;
typedef __attribute__((ext_vector_type(8))) unsigned short u16x8;
typedef __attribute__((ext_vector_type(4))) float f32x4;
typedef __attribute__((ext_vector_type(2))) unsigned uint2v;
typedef __attribute__((ext_vector_type(4))) unsigned uint4v;

#define DEVINL __device__ __forceinline__

constexpr int TB = 2;        // batch
constexpr int TT = 4096;     // seq len
constexpr int TD = 512;      // model dim
constexpr int TH = 8;        // heads
constexpr int THD = 64;      // head dim
constexpr int TM = TB * TT;  // 8192 flattened rows

// fp32 -> bf16 round-to-nearest-even
DEVINL unsigned short f2b(float f) {
  unsigned u = __builtin_bit_cast(unsigned, f);
  u += 0x7FFFu + ((u >> 16) & 1u);
  return (unsigned short)(u >> 16);
}

// pack 2 f32 -> 2 bf16 in one dword (lo -> low16, hi -> high16), RNE
DEVINL unsigned cvtpk(float lo, float hi) {
  unsigned r;
  asm("v_cvt_pk_bf16_f32 %0, %1, %2" : "=v"(r) : "v"(lo), "v"(hi));
  return r;
}

// barrier that only waits LDS ops (global stores may stay in flight)
DEVINL void lgkm_barrier() {
  asm volatile("s_waitcnt lgkmcnt(0)" ::: "memory");
  __builtin_amdgcn_s_barrier();
  __builtin_amdgcn_sched_barrier(0);
}

// ---------------------------------------------------------------------------
// GEMM: Y = X[M][512] @ W[512][512]^T  (torch Linear).
// MODE 0: bf16 row-major. MODE 1: fp32 + bias. MODE 2: bf16 per-head
// transposed VT[b][h][d][T] via swapped mfma operands.
// ---------------------------------------------------------------------------
template<int MODE>
__global__ __launch_bounds__(256, 2)
void gemm_xwt(const float* __restrict__ X, const float* __restrict__ W,
              unsigned short* __restrict__ Yb, float* __restrict__ Yf,
              const float* __restrict__ bias)
{
  constexpr int K = TD, N = TD;
  __shared__ unsigned short As[128][72];
  __shared__ unsigned short Bs[128][72];

  const int t    = threadIdx.x;
  const int lane = t & 63, w = t >> 6;
  const int fr = lane & 15, fq = lane >> 4;
  const int wr = (w >> 1) * 64, wc = (w & 1) * 64;
  const int bm = blockIdx.x * 128, bn = blockIdx.y * 128;
  const int srow = t >> 1;
  const int skh  = (t & 1) * 32;

  f32x4 acc[4][4];
  #pragma unroll
  for (int i = 0; i < 4; ++i)
    #pragma unroll
    for (int j = 0; j < 4; ++j)
      acc[i][j] = f32x4{0.f, 0.f, 0.f, 0.f};

  for (int k0 = 0; k0 < K; k0 += 64) {
    const float* srcA = X + (size_t)(bm + srow) * K + k0 + skh;
    const float* srcB = W + (size_t)(bn + srow) * K + k0 + skh;
    #pragma unroll
    for (int i = 0; i < 4; ++i) {
      float4 a0 = ((const float4*)srcA)[2 * i];
      float4 a1 = ((const float4*)srcA)[2 * i + 1];
      u16x8 oa = {f2b(a0.x), f2b(a0.y), f2b(a0.z), f2b(a0.w),
                  f2b(a1.x), f2b(a1.y), f2b(a1.z), f2b(a1.w)};
      *(u16x8*)&As[srow][skh + i * 8] = oa;
      float4 b0 = ((const float4*)srcB)[2 * i];
      float4 b1 = ((const float4*)srcB)[2 * i + 1];
      u16x8 ob = {f2b(b0.x), f2b(b0.y), f2b(b0.z), f2b(b0.w),
                  f2b(b1.x), f2b(b1.y), f2b(b1.z), f2b(b1.w)};
      *(u16x8*)&Bs[srow][skh + i * 8] = ob;
    }
    __syncthreads();
    #pragma unroll
    for (int kk = 0; kk < 2; ++kk) {
      bf16x8 af[4], bfv[4];
      #pragma unroll
      for (int i = 0; i < 4; ++i)
        af[i] = *(const bf16x8*)&As[wr + i * 16 + fr][kk * 32 + fq * 8];
      #pragma unroll
      for (int j = 0; j < 4; ++j)
        bfv[j] = *(const bf16x8*)&Bs[wc + j * 16 + fr][kk * 32 + fq * 8];
      #pragma unroll
      for (int i = 0; i < 4; ++i)
        #pragma unroll
        for (int j = 0; j < 4; ++j) {
          if (MODE == 2)
            acc[i][j] = __builtin_amdgcn_mfma_f32_16x16x32_bf16(bfv[i], af[j], acc[i][j], 0, 0, 0);
          else
            acc[i][j] = __builtin_amdgcn_mfma_f32_16x16x32_bf16(af[i], bfv[j], acc[i][j], 0, 0, 0);
        }
    }
    __syncthreads();
  }

  #pragma unroll
  for (int i = 0; i < 4; ++i) {
    #pragma unroll
    for (int j = 0; j < 4; ++j) {
      #pragma unroll
      for (int ii = 0; ii < 4; ++ii) {
        float v = acc[i][j][ii];
        if (MODE == 2) {
          const int Nidx = bn + wc + i * 16 + fq * 4 + ii;
          const int Midx = bm + wr + j * 16 + fr;
          const int h = Nidx >> 6, d = Nidx & (THD - 1);
          const int b = Midx >> 12, tt = Midx & (TT - 1);
          Yb[((size_t)(b * TH + h) * THD + d) * TT + tt] = f2b(v);
        } else {
          const int gm = bm + wr + i * 16 + fq * 4 + ii;
          const int gn = bn + wc + j * 16 + fr;
          if (MODE == 1) Yf[(size_t)gm * N + gn] = v + bias[gn];
          else           Yb[(size_t)gm * N + gn] = f2b(v);
        }
      }
    }
  }
}

// ---------------------------------------------------------------------------
// Fused attention, kv-split across waves. Block = (b,h,q-block of 64).
// Wave w owns kv rows w*16..w*16+15 of every 64-kv tile, computes S for all
// 64 q (Q held as 4 B-frags in regs). Swapped QK (mfma(K,Q)) puts q in the
// lane slot (fr) and kv in the k slot (fq,reg) -> the cvt_pk'd P IS the PV
// A-fragment: no LDS round trip for P. PV per tile-PAIR (k=32) with a custom
// k-order shared by P (A, dword order) and VT (B, lo/hi b64 reads).
// VT is QUAD-buffered (vbuf = tile & 3): pair p reads {(p&1)*2,(p&1)*2+1}
// while the in-loop stage writes ((p&1)*2)^2 -> no read/write overlap in any
// barrier interval (round-5 race fix). K stays double-buffered.
// Per-wave partial Z reduced across waves via LDS overlay at the end.
// ---------------------------------------------------------------------------
__global__ __launch_bounds__(256, 2)
void attn_fused(const unsigned short* __restrict__ Qb,
                const unsigned short* __restrict__ Kb,
                const unsigned short* __restrict__ VTg,
                float* __restrict__ attnO, float* __restrict__ Z)
{
  // Ks [2][64][72] @0 (18432B) | VTs [4][64][72] @18432 (36864B) | Lred @55296
  // Zs [64][68] fp32 overlays Ks after the kv loop.
  __shared__ __align__(16) char smem_[55552];
  auto Ks   = (unsigned short (*)[64][72])smem_;
  auto VTs  = (unsigned short (*)[64][72])(smem_ + 18432);
  float* Lred = (float*)(smem_ + 55296);      // [w][qf][fr] = [4][4][16]
  auto Zs   = (float (*)[68])smem_;           // [64 q][68 pitch]

  const int t    = threadIdx.x;
  const int lane = t & 63, w = t >> 6;        // w = 0..3 (kv quarter)
  const int fr = lane & 15, fq = lane >> 4;
  const int bh = blockIdx.y;                  // b*8+h
  const int b  = bh >> 3, h = bh & 7;
  const int q0 = blockIdx.x * 64;

  const size_t rowKV  = ((size_t)(b * TT)) * TD + h * THD;
  const size_t vtBase = (size_t)bh * THD * TT;

  const int tr = t >> 2;           // 0..63 staging row
  const int tc = (t & 3) * 16;     // 0,16,32,48

  auto loadK = [&](int kvt, u16x8& r0, u16x8& r1) {
    const unsigned short* src = Kb + rowKV + (size_t)(kvt * 64 + tr) * TD + tc;
    r0 = *(const u16x8*)src;
    r1 = *(const u16x8*)(src + 8);
  };
  auto loadVT = [&](int kvt, u16x8& r0, u16x8& r1) {
    const unsigned short* src = VTg + vtBase + (size_t)tr * TT + kvt * 64 + tc;
    r0 = *(const u16x8*)src;
    r1 = *(const u16x8*)(src + 8);
  };
  auto writeK = [&](int buf, const u16x8& r0, const u16x8& r1) {
    *(u16x8*)&Ks[buf][tr][tc]     = r0;
    *(u16x8*)&Ks[buf][tr][tc + 8] = r1;
  };
  auto writeVT = [&](int buf, const u16x8& r0, const u16x8& r1) {
    *(u16x8*)&VTs[buf][tr][tc]     = r0;
    *(u16x8*)&VTs[buf][tr][tc + 8] = r1;
  };

  // Q B-frags for the 4 q-groups (q = qf*16 + fr), held all kernel
  bf16x8 aq[4][2];
  #pragma unroll
  for (int qf = 0; qf < 4; ++qf) {
    const unsigned short* qsrc =
        Qb + ((size_t)(b * TT + q0 + qf * 16 + fr)) * TD + h * THD;
    aq[qf][0] = *(const bf16x8*)(qsrc + fq * 8);
    aq[qf][1] = *(const bf16x8*)(qsrc + 32 + fq * 8);
  }

  constexpr int NT = TT / 64;                  // 64 kv tiles
  constexpr float K2 = 0.18033688011112042f;   // (1/8) * log2(e)

  u16x8 kr0, kr1, vr0, vr1;
  loadK(0, kr0, kr1);
  writeK(0, kr0, kr1);
  lgkm_barrier();

  // ---- pass 1: denominators. lsum[qf] covers this wave's kv quarter ----
  float lsum[4] = {0.f, 0.f, 0.f, 0.f};
  for (int j = 0; j < NT; ++j) {
    const int cur = j & 1;
    if (j + 1 < NT) loadK(j + 1, kr0, kr1);
    bf16x8 ak0 = *(const bf16x8*)&Ks[cur][w * 16 + fr][fq * 8];
    bf16x8 ak1 = *(const bf16x8*)&Ks[cur][w * 16 + fr][32 + fq * 8];
    __builtin_amdgcn_s_setprio(1);
    #pragma unroll
    for (int qf = 0; qf < 4; ++qf) {
      f32x4 s = f32x4{0.f, 0.f, 0.f, 0.f};
      s = __builtin_amdgcn_mfma_f32_16x16x32_bf16(ak0, aq[qf][0], s, 0, 0, 0);
      s = __builtin_amdgcn_mfma_f32_16x16x32_bf16(ak1, aq[qf][1], s, 0, 0, 0);
      #pragma unroll
      for (int i = 0; i < 4; ++i)
        lsum[qf] += __builtin_amdgcn_exp2f(s[i] * K2);
    }
    __builtin_amdgcn_s_setprio(0);
    if (j + 1 < NT) writeK(cur ^ 1, kr0, kr1);
    lgkm_barrier();
  }
  // reduce over fq (kv sub-quarters), then across waves via LDS
  #pragma unroll
  for (int qf = 0; qf < 4; ++qf) {
    lsum[qf] += __shfl_xor(lsum[qf], 16, 64);
    lsum[qf] += __shfl_xor(lsum[qf], 32, 64);
  }
  if (fq == 0) {
    #pragma unroll
    for (int qf = 0; qf < 4; ++qf)
      Lred[(w * 4 + qf) * 16 + fr] = lsum[qf];
  }
  __syncthreads();
  float l2i[4];
  #pragma unroll
  for (int qf = 0; qf < 4; ++qf) {
    float s = Lred[(0 * 4 + qf) * 16 + fr] + Lred[(1 * 4 + qf) * 16 + fr] +
              Lred[(2 * 4 + qf) * 16 + fr] + Lred[(3 * 4 + qf) * 16 + fr];
    l2i[qf] = -__log2f(s);
  }

  // ---- pass 2: recompute, write attn, accumulate PV per tile pair ----
  loadK(0, kr0, kr1);
  loadVT(0, vr0, vr1);
  writeK(0, kr0, kr1);
  writeVT(0, vr0, vr1);
  lgkm_barrier();

  f32x4 accz[4][4];     // [qf][df] partial Z over this wave's kv
  #pragma unroll
  for (int i = 0; i < 4; ++i)
    #pragma unroll
    for (int j = 0; j < 4; ++j)
      accz[i][j] = f32x4{0.f, 0.f, 0.f, 0.f};

  unsigned pa[4][4];    // P as A-frag dwords: [qf][tile_half*2 + k]

  // QK for tile J: read Ks[J&1]; prefetch-load tile J+1 into regs.
#define QK_TILE(J, HALF)                                                       \
  {                                                                            \
    if ((J) + 1 < NT) { loadK((J) + 1, kr0, kr1); loadVT((J) + 1, vr0, vr1); } \
    bf16x8 ak0 = *(const bf16x8*)&Ks[(J) & 1][w * 16 + fr][fq * 8];            \
    bf16x8 ak1 = *(const bf16x8*)&Ks[(J) & 1][w * 16 + fr][32 + fq * 8];       \
    __builtin_amdgcn_s_setprio(1);                                             \
    _Pragma("unroll")                                                          \
    for (int qf = 0; qf < 4; ++qf) {                                           \
      f32x4 s = f32x4{0.f, 0.f, 0.f, 0.f};                                     \
      s = __builtin_amdgcn_mfma_f32_16x16x32_bf16(ak0, aq[qf][0], s, 0, 0, 0); \
      s = __builtin_amdgcn_mfma_f32_16x16x32_bf16(ak1, aq[qf][1], s, 0, 0, 0); \
      float p0 = __builtin_amdgcn_exp2f(fmaf(s[0], K2, l2i[qf]));              \
      float p1 = __builtin_amdgcn_exp2f(fmaf(s[1], K2, l2i[qf]));              \
      float p2 = __builtin_amdgcn_exp2f(fmaf(s[2], K2, l2i[qf]));              \
      float p3 = __builtin_amdgcn_exp2f(fmaf(s[3], K2, l2i[qf]));              \
      f32x4 pv4 = {p0, p1, p2, p3};                                            \
      __builtin_nontemporal_store(pv4,                                         \
        (f32x4*)(attnO + ((size_t)bh * TT + q0 + qf * 16 + fr) * TT            \
                 + (J) * 64 + w * 16 + fq * 4));                               \
      pa[qf][(HALF) * 2 + 0] = cvtpk(p0, p1);                                  \
      pa[qf][(HALF) * 2 + 1] = cvtpk(p2, p3);                                  \
    }                                                                          \
    __builtin_amdgcn_s_setprio(0);                                             \
  }
  // stage tile J+1: K -> Ks[(J+1)&1], VT -> VTs[(J+1)&3]; then barrier.
#define STAGE_TAIL(J)                                                          \
  {                                                                            \
    if ((J) + 1 < NT) {                                                        \
      writeK(((J) + 1) & 1, kr0, kr1);                                         \
      writeVT(((J) + 1) & 3, vr0, vr1);                                        \
    }                                                                          \
    lgkm_barrier();                                                            \
  }

  for (int jp = 0; jp < NT / 2; ++jp) {
    const int j0 = jp * 2;
    const int vb = (jp & 1) * 2;      // VT buffers for this pair: vb, vb+1
    QK_TILE(j0, 0)
    STAGE_TAIL(j0)
    QK_TILE(j0 + 1, 1)
    // PV over the pair. k-order: k = fq*8+e -> kv = (e>>2)*64 + w*16 + fq*4
    // + (e&3), shared by P (A) and V (B).
    __builtin_amdgcn_s_setprio(1);
    #pragma unroll
    for (int df = 0; df < 4; ++df) {
      uint2v lo = *(const uint2v*)&VTs[vb][df * 16 + fr][w * 16 + fq * 4];
      uint2v hi = *(const uint2v*)&VTs[vb + 1][df * 16 + fr][w * 16 + fq * 4];
      uint4v bvv = {lo[0], lo[1], hi[0], hi[1]};
      bf16x8 bv = __builtin_bit_cast(bf16x8, bvv);
      #pragma unroll
      for (int qf = 0; qf < 4; ++qf) {
        uint4v pav = {pa[qf][0], pa[qf][1], pa[qf][2], pa[qf][3]};
        accz[qf][df] = __builtin_amdgcn_mfma_f32_16x16x32_bf16(
            __builtin_bit_cast(bf16x8, pav), bv, accz[qf][df], 0, 0, 0);
      }
    }
    __builtin_amdgcn_s_setprio(0);
    STAGE_TAIL(j0 + 1)
  }
#undef QK_TILE
#undef STAGE_TAIL

  // ---- cross-wave Z reduction via Zs overlay (on Ks; safe after barrier) --
  for (int ww = 0; ww < 4; ++ww) {
    if (w == ww) {
      #pragma unroll
      for (int qf = 0; qf < 4; ++qf)
        #pragma unroll
        for (int df = 0; df < 4; ++df)
          #pragma unroll
          for (int i = 0; i < 4; ++i) {
            float* zp = &Zs[qf * 16 + fq * 4 + i][df * 16 + fr];
            float v = accz[qf][df][i];
            if (ww != 0) v += *zp;
            *zp = v;
          }
    }
    __syncthreads();
  }
  // Z in [B*T, D] layout (head transpose folded into addressing)
  {
    const int r = t >> 2, c4 = (t & 3) * 16;
    float* zdst = Z + (size_t)(b * TT + q0 + r) * TD + h * THD + c4;
    #pragma unroll
    for (int i = 0; i < 4; ++i)
      *(f32x4*)(zdst + i * 4) = *(const f32x4*)&Zs[r][c4 + i * 4];
  }
}

// ---------------------------------------------------------------------------
extern "C" void kernel_launch(void* const* d_in, const int* in_sizes, int n_in,
                              void* d_out, int out_size, void* d_ws, size_t ws_size,
                              hipStream_t stream) {
  const float* queries = (const float*)d_in[0];
  const float* keys    = (const float*)d_in[1];
  const float* values  = (const float*)d_in[2];
  const float* Wq = (const float*)d_in[3];
  const float* Wk = (const float*)d_in[4];
  const float* Wv = (const float*)d_in[5];
  const float* Wo = (const float*)d_in[6];
  const float* bo = (const float*)d_in[7];

  float* out  = (float*)d_out;                       // [2,4096,512]
  float* attn = out + (size_t)TM * TD;               // [2,8,4096,4096]

  unsigned short* qb = (unsigned short*)d_ws;
  unsigned short* kb = qb + (size_t)TM * TD;
  unsigned short* vt = kb + (size_t)TM * TD;
  float*          zf = (float*)(vt + (size_t)TM * TD);

  dim3 gg(TM / 128, TD / 128), bb(256);
  gemm_xwt<0><<<gg, bb, 0, stream>>>(queries, Wq, qb, nullptr, nullptr);
  gemm_xwt<0><<<gg, bb, 0, stream>>>(keys,    Wk, kb, nullptr, nullptr);
  gemm_xwt<2><<<gg, bb, 0, stream>>>(values,  Wv, vt, nullptr, nullptr);

  attn_fused<<<dim3(TT / 64, TB * TH), bb, 0, stream>>>(qb, kb, vt, attn, zf);

  gemm_xwt<1><<<gg, bb, 0, stream>>>(zf, Wo, nullptr, out, bo);
}